// Round 2
// baseline (238.527 us; speedup 1.0000x reference)
//
#include <hip/hip_runtime.h>
#include <cstdint>
#include <cmath>

#define QP    127.0f
#define MINR  1e-6f

// Problem dims: B*N = 8192 tokens, D = 1024, H = 4096
#define MTOK 8192
#define DDIM 1024
#define HDIM 4096

typedef __attribute__((ext_vector_type(4))) int int32x4;

__device__ __forceinline__ void gload16(const void* g, void* l) {
    __builtin_amdgcn_global_load_lds(
        (const __attribute__((address_space(1))) void*)g,
        (__attribute__((address_space(3))) void*)l, 16, 0, 0);
}

template<int N> __device__ __forceinline__ void wait_vmcnt() {
    static_assert(N == 0 || N == 3 || N == 4, "add vmcnt case");
    if constexpr (N == 0) asm volatile("s_waitcnt vmcnt(0)" ::: "memory");
    else if constexpr (N == 3) asm volatile("s_waitcnt vmcnt(3)" ::: "memory");
    else if constexpr (N == 4) asm volatile("s_waitcnt vmcnt(4)" ::: "memory");
}

// raw barrier + compiler-only memory fence: the fence AFTER s_barrier keeps
// global_load_lds issues (and LDS reads) from hoisting across the barrier —
// llvm models s_barrier as IntrNoMem, so without the fence a prefetch could
// be issued before other waves finish reading the region it overwrites.
__device__ __forceinline__ void barrier_fence() {
    __builtin_amdgcn_s_barrier();
    asm volatile("" ::: "memory");
}

__global__ void zero_scales_kernel(float* g) {
    if (threadIdx.x < 4) g[threadIdx.x] = 0.0f;
}

__global__ void absmax_kernel(const float* __restrict__ in, int n4, float* __restrict__ gout) {
    const float4* in4 = (const float4*)in;
    int tid = blockIdx.x * blockDim.x + threadIdx.x;
    int stride = gridDim.x * blockDim.x;
    float m = 0.0f;
    for (int i = tid; i < n4; i += stride) {
        float4 v = in4[i];
        m = fmaxf(m, fmaxf(fmaxf(fabsf(v.x), fabsf(v.y)), fmaxf(fabsf(v.z), fabsf(v.w))));
    }
    #pragma unroll
    for (int off = 32; off; off >>= 1) m = fmaxf(m, __shfl_down(m, off));
    __shared__ float sm[4];
    int lane = threadIdx.x & 63, w = threadIdx.x >> 6;
    if (lane == 0) sm[w] = m;
    __syncthreads();
    if (threadIdx.x == 0) {
        float bm = fmaxf(fmaxf(sm[0], sm[1]), fmaxf(sm[2], sm[3]));
        atomicMax((int*)gout, __float_as_int(bm));
    }
}

__global__ void quant_kernel(const float* __restrict__ in, int8_t* __restrict__ out,
                             int n4, const float* __restrict__ gm) {
    const float s = fmaxf(*gm, MINR) / QP;
    const float4* in4 = (const float4*)in;
    int* out4 = (int*)out;
    int tid = blockIdx.x * blockDim.x + threadIdx.x;
    int stride = gridDim.x * blockDim.x;
    for (int i = tid; i < n4; i += stride) {
        float4 v = in4[i];
        int q0 = ((int)rintf(v.x / s)) & 255;
        int q1 = ((int)rintf(v.y / s)) & 255;
        int q2 = ((int)rintf(v.z / s)) & 255;
        int q3 = ((int)rintf(v.w / s)) & 255;
        out4[i] = q0 | (q1 << 8) | (q2 << 16) | (q3 << 24);
    }
}

// ---------------------------------------------------------------------------
// 256-wide 8-phase i8 GEMM (T2 swizzle + T3/T4 counted vmcnt + T5 setprio +
// T1 XCD swizzle).  C = A[M x KD] @ B[ND x KD]^T, int8 inputs, fp32 epilogue.
// BM=256, BK=128 bytes, 8 waves (2M x 4N), per-wave output 128 x (BN/4).
// LDS: 2 dbuf slots x (A 32KB + B BN/8 KB).  Stage unit = half-tile:
//   A-half h = rows read by quadrants with mh==h; B-half h = rows with nh==h.
// Stage schedule (phase -> target), derived so each stage lands one phase
// after its region's last read, with vmcnt(LA+LB) checkpoints at phases 3,7:
//   p0: T(2t+1) A1 -> slot1     p4: T(2t+2) A1 -> slot0
//   p1: T(2t+1) B1 -> slot1     p5: T(2t+2) B1 -> slot0
//   p2: T(2t+2) A0 -> slot0     p6: T(2t+3) A0 -> slot1
//   p3: T(2t+2) B0 -> slot0     p7: T(2t+3) B0 -> slot1
// Last iter: p2..p7 stages guarded off -> p3 must drain vmcnt(0) (the counted
// wait would otherwise leave p0/p1's loads in flight for phases 4-7's reads).
// ---------------------------------------------------------------------------
template<int KD, int ND, int BN, bool GELU>
__global__ __launch_bounds__(512, 2)
void gemm8_i8(const int8_t* __restrict__ A, const int8_t* __restrict__ B,
              const float* __restrict__ bias,
              const float* __restrict__ gmA, const float* __restrict__ gmB,
              float* __restrict__ out, float* __restrict__ omax) {
    constexpr int BM = 256;
    constexpr int KT = KD / 128;          // K-tiles
    constexpr int ITERS = KT / 2;
    constexpr int LA = BM / 128;          // gload instrs / thread / A-half (2)
    constexpr int LB = BN / 128;          // 2 (BN=256) or 1 (BN=128)
    constexpr int VMC = LA + LB;          // counted-vmcnt allowance
    constexpr int QA = BM / 4;            // A half-granularity rows (64)
    constexpr int QB = BN / 8;            // B half-granularity rows (32/16)
    constexpr int NR = BN / 64;           // N fragments per wave (4/2)
    constexpr int NQ = NR / 2;            // N frags per quadrant (2/1)
    constexpr int NTILES = ND / BN;

    __shared__ int8_t lA[2 * BM * 128];
    __shared__ int8_t lB[2 * BN * 128];
    __shared__ float red[8];

    const int t = threadIdx.x;
    const int lane = t & 63;
    const int w = t >> 6;
    const int wr = w >> 2;                // 0..1
    const int wc = w & 3;                 // 0..3
    const int lr = lane & 15;
    const int lg = lane >> 4;

    // T1: bijective XCD swizzle (gridDim.x % 8 == 0 by construction)
    const int nwg = gridDim.x;
    const int orig = blockIdx.x;
    const int wg = (orig & 7) * (nwg >> 3) + (orig >> 3);
    const int bc = wg % NTILES;
    const int br = wg / NTILES;

    const int8_t* Abase = A + (size_t)br * BM * KD;
    const int8_t* Bbase = B + (size_t)bc * BN * KD;

    // per-thread staging offsets (compile-time indexed only -> registers)
    int offAg[2][LA], offAl[2][LA], offBg[2][LB], offBl[2][LB];
    #pragma unroll
    for (int h = 0; h < 2; ++h) {
        #pragma unroll
        for (int i = 0; i < LA; ++i) {
            int c = i * 512 + t, r = c >> 3, sl = c & 7;
            int gr = (r % QA) + h * QA + (r / QA) * 2 * QA;
            offAg[h][i] = gr * KD + ((sl ^ (gr & 7)) << 4);   // src pre-swizzled
            offAl[h][i] = gr * 128 + sl * 16;                 // linear LDS dest
        }
        #pragma unroll
        for (int i = 0; i < LB; ++i) {
            int c = i * 512 + t, r = c >> 3, sl = c & 7;
            int gr = (r % QB) + h * QB + (r / QB) * 2 * QB;
            offBg[h][i] = gr * KD + ((sl ^ (gr & 7)) << 4);
            offBl[h][i] = gr * 128 + sl * 16;
        }
    }

#define STAGE_A(kt, h, s) { _Pragma("unroll") for (int i_ = 0; i_ < LA; ++i_) \
        gload16(Abase + (kt) * 128 + offAg[h][i_], &lA[(s) * BM * 128 + offAl[h][i_]]); }
#define STAGE_B(kt, h, s) { _Pragma("unroll") for (int i_ = 0; i_ < LB; ++i_) \
        gload16(Bbase + (kt) * 128 + offBg[h][i_], &lB[(s) * BN * 128 + offBl[h][i_]]); }

    // ds_read bases: row & 7 == lr & 7 (all other row terms are multiples of 16)
    const int baseA0 = (wr * 128 + lr) * 128;
    const int baseB0 = (wc * (BN / 4) + lr) * 128;
    const int sw0 = ((0 + lg) ^ (lr & 7)) << 4;
    const int sw1 = ((4 + lg) ^ (lr & 7)) << 4;

    int32x4 acc[8][NR] = {};

// one phase: quadrant (mh,nh) of slot s; 12 (or 10) ds_read_b128 -> stage ->
// barrier -> lgkmcnt(0) -> setprio-bracketed MFMA cluster.
#define PHASE(P, ...) do {                                                           \
        constexpr int s_ = (P) >> 2, mh_ = ((P) >> 1) & 1, nh_ = (P) & 1;            \
        int32x4 af[4][2], bf[NQ][2];                                                 \
        _Pragma("unroll") for (int m = 0; m < 4; ++m) {                              \
            af[m][0] = *(const int32x4*)&lA[s_ * BM * 128 + baseA0 + (mh_ * 64 + m * 16) * 128 + sw0]; \
            af[m][1] = *(const int32x4*)&lA[s_ * BM * 128 + baseA0 + (mh_ * 64 + m * 16) * 128 + sw1]; \
        }                                                                            \
        _Pragma("unroll") for (int n = 0; n < NQ; ++n) {                             \
            bf[n][0] = *(const int32x4*)&lB[s_ * BN * 128 + baseB0 + (nh_ * QB + n * 16) * 128 + sw0]; \
            bf[n][1] = *(const int32x4*)&lB[s_ * BN * 128 + baseB0 + (nh_ * QB + n * 16) * 128 + sw1]; \
        }                                                                            \
        __VA_ARGS__;                                                                 \
        barrier_fence();                                                             \
        asm volatile("s_waitcnt lgkmcnt(0)" ::: "memory");                           \
        __builtin_amdgcn_s_setprio(1);                                               \
        _Pragma("unroll") for (int m = 0; m < 4; ++m)                                \
            _Pragma("unroll") for (int n = 0; n < NQ; ++n) {                         \
                acc[mh_ * 4 + m][nh_ * NQ + n] = __builtin_amdgcn_mfma_i32_16x16x64_i8( \
                    af[m][0], bf[n][0], acc[mh_ * 4 + m][nh_ * NQ + n], 0, 0, 0);    \
                acc[mh_ * 4 + m][nh_ * NQ + n] = __builtin_amdgcn_mfma_i32_16x16x64_i8( \
                    af[m][1], bf[n][1], acc[mh_ * 4 + m][nh_ * NQ + n], 0, 0, 0);    \
            }                                                                        \
        __builtin_amdgcn_s_setprio(0);                                               \
    } while (0)

    // prologue: T0 complete + T1 A0,B0; wait until T0 fully landed
    STAGE_A(0, 0, 0); STAGE_B(0, 0, 0); STAGE_A(0, 1, 0); STAGE_B(0, 1, 0);
    STAGE_A(1, 0, 1); STAGE_B(1, 0, 1);
    wait_vmcnt<VMC>();
    barrier_fence();

    for (int it = 0; it < ITERS; ++it) {
        const int k0 = 2 * it;
        const bool more = (it < ITERS - 1);

        PHASE(0, STAGE_A(k0 + 1, 1, 1));
        barrier_fence();
        PHASE(1, STAGE_B(k0 + 1, 1, 1));
        barrier_fence();
        PHASE(2, if (more) STAGE_A(k0 + 2, 0, 0));
        barrier_fence();
        PHASE(3, if (more) STAGE_B(k0 + 2, 0, 0));
        if (more) wait_vmcnt<VMC>(); else wait_vmcnt<0>();
        barrier_fence();
        PHASE(4, if (more) STAGE_A(k0 + 2, 1, 0));
        barrier_fence();
        PHASE(5, if (more) STAGE_B(k0 + 2, 1, 0));
        barrier_fence();
        PHASE(6, if (more) STAGE_A(k0 + 3, 0, 1));
        barrier_fence();
        PHASE(7, if (more) STAGE_B(k0 + 3, 0, 1));
        wait_vmcnt<VMC>();
        barrier_fence();
    }
#undef PHASE
#undef STAGE_A
#undef STAGE_B

    // epilogue: (acc + bias) * (sB*sA), optional exact gelu + absmax reduce
    const float sA = fmaxf(*gmA, MINR) / QP;
    const float sB = fmaxf(*gmB, MINR) / QP;
    const float sc = sB * sA;
    float lmax = 0.0f;
    const int rowb = br * BM + wr * 128 + lg * 4;
    const int colb = bc * BN + wc * (BN / 4) + lr;
    #pragma unroll
    for (int m = 0; m < 8; ++m) {
        #pragma unroll
        for (int n = 0; n < NR; ++n) {
            #pragma unroll
            for (int r = 0; r < 4; ++r) {
                int row = rowb + m * 16 + r;
                int col = colb + n * 16;
                float f = (float)acc[m][n][r] + bias[col];
                f *= sc;
                if (GELU) {
                    float g = f * (erff(f / 1.41421356237309504880f) + 1.0f) * 0.5f;
                    out[(size_t)row * ND + col] = g;
                    lmax = fmaxf(lmax, fabsf(g));
                } else {
                    out[(size_t)row * ND + col] = f;
                }
            }
        }
    }
    if (GELU) {
        #pragma unroll
        for (int off = 32; off; off >>= 1) lmax = fmaxf(lmax, __shfl_down(lmax, off));
        if (lane == 0) red[w] = lmax;
        __syncthreads();
        if (t == 0) {
            float bm = red[0];
            #pragma unroll
            for (int i = 1; i < 8; ++i) bm = fmaxf(bm, red[i]);
            atomicMax((int*)omax, __float_as_int(bm));
        }
    }
}

extern "C" void kernel_launch(void* const* d_in, const int* in_sizes, int n_in,
                              void* d_out, int out_size, void* d_ws, size_t ws_size,
                              hipStream_t stream) {
    const float* x  = (const float*)d_in[0];   // [8192, 1024]
    const float* w1 = (const float*)d_in[1];   // [4096, 1024]
    const float* b1 = (const float*)d_in[2];   // [4096]
    const float* w2 = (const float*)d_in[3];   // [1024, 4096]
    const float* b2 = (const float*)d_in[4];   // [1024]
    float* out = (float*)d_out;                // [8192, 1024]

    uint8_t* ws = (uint8_t*)d_ws;
    float*  gmax = (float*)ws;                           // [0]=x [1]=w1 [2]=h [3]=w2
    int8_t* xq   = (int8_t*)(ws + 256);
    int8_t* w1q  = xq  + (size_t)MTOK * DDIM;
    int8_t* w2q  = w1q + (size_t)HDIM * DDIM;
    int8_t* hq   = w2q + (size_t)DDIM * HDIM;
    float*  h    = (float*)(hq + (size_t)MTOK * HDIM);   // 128 MiB fp32

    zero_scales_kernel<<<1, 64, 0, stream>>>(gmax);

    absmax_kernel<<<1024, 256, 0, stream>>>(x,  MTOK * DDIM / 4, gmax + 0);
    absmax_kernel<<<512,  256, 0, stream>>>(w1, HDIM * DDIM / 4, gmax + 1);
    absmax_kernel<<<512,  256, 0, stream>>>(w2, DDIM * HDIM / 4, gmax + 3);

    quant_kernel<<<2048, 256, 0, stream>>>(x,  xq,  MTOK * DDIM / 4, gmax + 0);
    quant_kernel<<<1024, 256, 0, stream>>>(w1, w1q, HDIM * DDIM / 4, gmax + 1);
    quant_kernel<<<1024, 256, 0, stream>>>(w2, w2q, DDIM * HDIM / 4, gmax + 3);

    // h = gelu((xq @ w1q^T + b1) * s1), fused absmax(h) -> gmax[2]
    // grid = (8192/256)*(4096/256) = 512 blocks
    gemm8_i8<DDIM, HDIM, 256, true>
        <<<512, 512, 0, stream>>>(xq, w1q, b1, gmax + 0, gmax + 1, h, gmax + 2);

    quant_kernel<<<4096, 256, 0, stream>>>(h, hq, MTOK * HDIM / 4, gmax + 2);

    // out = (hq @ w2q^T + b2) * s2 ; grid = (8192/256)*(1024/128) = 256 blocks
    gemm8_i8<HDIM, DDIM, 128, false>
        <<<256, 512, 0, stream>>>(hq, w2q, b2, gmax + 2, gmax + 3, out, nullptr);
}

// Round 3
// 208.317 us; speedup vs baseline: 1.1450x; 1.1450x over previous
//
#include <hip/hip_runtime.h>
#include <cstdint>
#include <cmath>

#define QP    127.0f
#define MINR  1e-6f

// Problem dims: B*N = 8192 tokens, D = 1024, H = 4096
#define MTOK 8192
#define DDIM 1024
#define HDIM 4096

typedef __attribute__((ext_vector_type(4))) int int32x4;

__device__ __forceinline__ void gload16(const void* g, void* l) {
    __builtin_amdgcn_global_load_lds(
        (const __attribute__((address_space(1))) void*)g,
        (__attribute__((address_space(3))) void*)l, 16, 0, 0);
}

__global__ void zero_scales_kernel(float* g) {
    if (threadIdx.x < 4) g[threadIdx.x] = 0.0f;
}

// ---- fused 3-tensor absmax: block-range partition, atomicMax per tensor ----
__device__ __forceinline__ float wave_block_max(float m) {
    #pragma unroll
    for (int off = 32; off; off >>= 1) m = fmaxf(m, __shfl_down(m, off));
    __shared__ float sm[4];
    int lane = threadIdx.x & 63, w = threadIdx.x >> 6;
    if (lane == 0) sm[w] = m;
    __syncthreads();
    float bm = 0.0f;
    if (threadIdx.x == 0) bm = fmaxf(fmaxf(sm[0], sm[1]), fmaxf(sm[2], sm[3]));
    return bm;
}

__device__ __forceinline__ void absmax_range(const float4* in4, int n4, int bid, int nb,
                                             float* gout) {
    int tid = bid * blockDim.x + threadIdx.x;
    int stride = nb * blockDim.x;
    float m = 0.0f;
    for (int i = tid; i < n4; i += stride) {
        float4 v = in4[i];
        m = fmaxf(m, fmaxf(fmaxf(fabsf(v.x), fabsf(v.y)), fmaxf(fabsf(v.z), fabsf(v.w))));
    }
    float bm = wave_block_max(m);
    if (threadIdx.x == 0) atomicMax((int*)gout, __float_as_int(bm));
}

// blocks [0,1024) -> x, [1024,1536) -> w1, [1536,2048) -> w2
__global__ void absmax3_kernel(const float* __restrict__ x, const float* __restrict__ w1,
                               const float* __restrict__ w2, float* __restrict__ gmax) {
    int b = blockIdx.x;
    if (b < 1024)      absmax_range((const float4*)x,  MTOK * DDIM / 4, b,        1024, gmax + 0);
    else if (b < 1536) absmax_range((const float4*)w1, HDIM * DDIM / 4, b - 1024,  512, gmax + 1);
    else               absmax_range((const float4*)w2, DDIM * HDIM / 4, b - 1536,  512, gmax + 3);
}

__device__ __forceinline__ void quant_range(const float4* in4, int* out4, int n4,
                                            int bid, int nb, const float* gm) {
    const float s = fmaxf(*gm, MINR) / QP;
    int tid = bid * blockDim.x + threadIdx.x;
    int stride = nb * blockDim.x;
    for (int i = tid; i < n4; i += stride) {
        float4 v = in4[i];
        int q0 = ((int)rintf(v.x / s)) & 255;
        int q1 = ((int)rintf(v.y / s)) & 255;
        int q2 = ((int)rintf(v.z / s)) & 255;
        int q3 = ((int)rintf(v.w / s)) & 255;
        out4[i] = q0 | (q1 << 8) | (q2 << 16) | (q3 << 24);
    }
}

// blocks [0,2048) -> x, [2048,3072) -> w1, [3072,4096) -> w2
__global__ void quant3_kernel(const float* __restrict__ x, const float* __restrict__ w1,
                              const float* __restrict__ w2, int8_t* __restrict__ xq,
                              int8_t* __restrict__ w1q, int8_t* __restrict__ w2q,
                              const float* __restrict__ gmax) {
    int b = blockIdx.x;
    if (b < 2048)      quant_range((const float4*)x,  (int*)xq,  MTOK * DDIM / 4, b,        2048, gmax + 0);
    else if (b < 3072) quant_range((const float4*)w1, (int*)w1q, HDIM * DDIM / 4, b - 2048, 1024, gmax + 1);
    else               quant_range((const float4*)w2, (int*)w2q, DDIM * HDIM / 4, b - 3072, 1024, gmax + 3);
}

__global__ void quant_kernel(const float* __restrict__ in, int8_t* __restrict__ out,
                             int n4, const float* __restrict__ gm) {
    quant_range((const float4*)in, (int*)out, n4, blockIdx.x, gridDim.x, gm);
}

// ---------------------------------------------------------------------------
// Round-1 proven GEMM structure (128x128 tile, BK=128, 4 waves,
// mfma_i32_16x16x64_i8, linear-dest global_load_lds + source pre-swizzle,
// XOR-swizzled ds_read_b128) with two added levers:
//   - __launch_bounds__(256,3): 3 blocks/CU co-resident (was 2) so the
//     vmcnt(0)+barrier stage-drain of one block hides under other blocks'
//     MFMA. Reg budget: ~136 unified (72+64 acc) fits the 170 cap w/ slack.
//   - T1 bijective XCD swizzle, br-fastest: each XCD owns a contiguous set
//     of bc columns -> its B-tiles stay pinned in the per-XCD L2.
// grid is 1D, %8 == 0 (2048 for GEMM1, 512 for GEMM2).
// ---------------------------------------------------------------------------
template<int KD, int ND, bool GELU_EPI>
__global__ __launch_bounds__(256, 3)
void gemm_i8_kernel(const int8_t* __restrict__ A, const int8_t* __restrict__ B,
                    const float* __restrict__ bias,
                    const float* __restrict__ gmA, const float* __restrict__ gmB,
                    float* __restrict__ out, float* __restrict__ omax) {
    __shared__ int8_t lA[128 * 128];
    __shared__ int8_t lB[128 * 128];
    const int t = threadIdx.x;
    const int lane = t & 63;
    const int w = t >> 6;
    const int wm = (w >> 1) * 64;
    const int wn = (w & 1) * 64;
    const int lr = lane & 15;
    const int lg = lane >> 4;

    // XCD swizzle: nwg % 8 == 0 -> bijective. br fastest (MTOK/128 = 64 rows)
    const int chunk = gridDim.x >> 3;
    const int logical = (blockIdx.x & 7) * chunk + (blockIdx.x >> 3);
    const int br = logical & 63;          // MTOK/128 == 64
    const int bc = logical >> 6;

    const int8_t* Ab = A + (size_t)br * 128 * KD;
    const int8_t* Bb = B + (size_t)bc * 128 * KD;

    int32x4 acc[4][4] = {};

    for (int kt = 0; kt < KD / 128; ++kt) {
        #pragma unroll
        for (int i = 0; i < 4; ++i) {
            int c = t + i * 256;          // 0..1023
            int r = c >> 3;               // tile row 0..127
            int sl = c & 7;               // 16B slot 0..7
            int sc = ((sl ^ (r & 7)) << 4);
            gload16(Ab + (size_t)r * KD + kt * 128 + sc, &lA[c * 16]);
            gload16(Bb + (size_t)r * KD + kt * 128 + sc, &lB[c * 16]);
        }
        __syncthreads();

        #pragma unroll
        for (int kk = 0; kk < 2; ++kk) {
            int32x4 af[4], bf[4];
            #pragma unroll
            for (int m = 0; m < 4; ++m) {
                int r = wm + m * 16 + lr;
                int g = kk * 4 + lg;
                af[m] = *(const int32x4*)&lA[r * 128 + ((g ^ (r & 7)) << 4)];
            }
            #pragma unroll
            for (int n = 0; n < 4; ++n) {
                int r = wn + n * 16 + lr;
                int g = kk * 4 + lg;
                bf[n] = *(const int32x4*)&lB[r * 128 + ((g ^ (r & 7)) << 4)];
            }
            #pragma unroll
            for (int m = 0; m < 4; ++m)
                #pragma unroll
                for (int n = 0; n < 4; ++n)
                    acc[m][n] = __builtin_amdgcn_mfma_i32_16x16x64_i8(af[m], bf[n], acc[m][n], 0, 0, 0);
        }
        __syncthreads();
    }

    // epilogue — replicate reference fp32 op order exactly
    const float sA = fmaxf(*gmA, MINR) / QP;
    const float sB = fmaxf(*gmB, MINR) / QP;
    const float s = sB * sA;
    float lmax = 0.0f;
    #pragma unroll
    for (int m = 0; m < 4; ++m) {
        #pragma unroll
        for (int n = 0; n < 4; ++n) {
            #pragma unroll
            for (int r = 0; r < 4; ++r) {
                int row = br * 128 + wm + m * 16 + lg * 4 + r;
                int col = bc * 128 + wn + n * 16 + lr;
                float f = (float)acc[m][n][r] + bias[col];
                f *= s;
                if (GELU_EPI) {
                    float gg = f * (erff(f / 1.41421356237309504880f) + 1.0f) * 0.5f;
                    out[(size_t)row * ND + col] = gg;
                    lmax = fmaxf(lmax, fabsf(gg));
                } else {
                    out[(size_t)row * ND + col] = f;
                }
            }
        }
    }
    if (GELU_EPI) {
        #pragma unroll
        for (int off = 32; off; off >>= 1) lmax = fmaxf(lmax, __shfl_down(lmax, off));
        __shared__ float red[4];
        if (lane == 0) red[w] = lmax;
        __syncthreads();
        if (t == 0) {
            float bm = fmaxf(fmaxf(red[0], red[1]), fmaxf(red[2], red[3]));
            atomicMax((int*)omax, __float_as_int(bm));
        }
    }
}

extern "C" void kernel_launch(void* const* d_in, const int* in_sizes, int n_in,
                              void* d_out, int out_size, void* d_ws, size_t ws_size,
                              hipStream_t stream) {
    const float* x  = (const float*)d_in[0];   // [8192, 1024]
    const float* w1 = (const float*)d_in[1];   // [4096, 1024]
    const float* b1 = (const float*)d_in[2];   // [4096]
    const float* w2 = (const float*)d_in[3];   // [1024, 4096]
    const float* b2 = (const float*)d_in[4];   // [1024]
    float* out = (float*)d_out;                // [8192, 1024]

    uint8_t* ws = (uint8_t*)d_ws;
    float*  gmax = (float*)ws;                           // [0]=x [1]=w1 [2]=h [3]=w2
    int8_t* xq   = (int8_t*)(ws + 256);
    int8_t* w1q  = xq  + (size_t)MTOK * DDIM;
    int8_t* w2q  = w1q + (size_t)HDIM * DDIM;
    int8_t* hq   = w2q + (size_t)DDIM * HDIM;
    float*  h    = (float*)(hq + (size_t)MTOK * HDIM);   // 128 MiB fp32

    zero_scales_kernel<<<1, 64, 0, stream>>>(gmax);

    absmax3_kernel<<<2048, 256, 0, stream>>>(x, w1, w2, gmax);
    quant3_kernel<<<4096, 256, 0, stream>>>(x, w1, w2, xq, w1q, w2q, gmax);

    // h = gelu((xq @ w1q^T + b1) * s1), fused absmax(h) -> gmax[2]
    // grid = 64*32 = 2048 (%8==0)
    gemm_i8_kernel<DDIM, HDIM, true>
        <<<2048, 256, 0, stream>>>(xq, w1q, b1, gmax + 0, gmax + 1, h, gmax + 2);

    quant_kernel<<<4096, 256, 0, stream>>>(h, hq, MTOK * HDIM / 4, gmax + 2);

    // out = (hq @ w2q^T + b2) * s2 ; grid = 64*8 = 512 (%8==0)
    gemm_i8_kernel<HDIM, DDIM, false>
        <<<512, 256, 0, stream>>>(hq, w2q, b2, gmax + 2, gmax + 3, out, nullptr);
}